// Round 18
// baseline (375.085 us; speedup 1.0000x reference)
//
#include <hip/hip_runtime.h>
#include <hip/hip_bf16.h>

#define BB 16
#define CC 2048
#define HWW 1024
#define DD 256
#define BN_RSQRT 0.9999950000374997f

typedef short bf16x8 __attribute__((ext_vector_type(8)));
typedef float f32x4 __attribute__((ext_vector_type(4)));
typedef unsigned short u16x8 __attribute__((ext_vector_type(8)));
typedef unsigned short u16x4 __attribute__((ext_vector_type(4)));
typedef unsigned short u16;

typedef __attribute__((address_space(1))) const unsigned GU;
typedef __attribute__((address_space(3))) unsigned LU;
__device__ __forceinline__ void gload16(const void* g, void* l) {
    __builtin_amdgcn_global_load_lds((GU*)g, (LU*)l, 16, 0, 0);
}

// ---- bf16 split helpers (RNE) ----
__device__ __forceinline__ unsigned short f2bf(float x) {
    unsigned u = __builtin_bit_cast(unsigned, x);
    unsigned r = u + 0x7FFFu + ((u >> 16) & 1u);
    return (unsigned short)(r >> 16);
}
__device__ __forceinline__ float bf2f(unsigned short h) {
    unsigned u = ((unsigned)h) << 16;
    return __builtin_bit_cast(float, u);
}
__device__ __forceinline__ void split2(float x, unsigned short& hi, unsigned short& lo) {
    hi = f2bf(x);
    lo = f2bf(x - bf2f(hi));
}

struct RegsA { u16x8 h[2]; u16x8 l[2]; };
struct RegsB { u16x8 h[2]; u16x8 l[2]; };

// ---------------------------------------------------------------------------
// split fp32 -> hi/lo bf16 planes (weights)
// ---------------------------------------------------------------------------
__global__ __launch_bounds__(256) void split_k(const float* __restrict__ in,
                                               u16* __restrict__ hi, u16* __restrict__ lo,
                                               long long n8) {
    long long i = (long long)blockIdx.x * 256 + threadIdx.x;
    if (i >= n8) return;
    const float4* p = (const float4*)in + i * 2;
    float4 a = p[0], b = p[1];
    float xs[8] = {a.x, a.y, a.z, a.w, b.x, b.y, b.z, b.w};
    u16x8 h, l;
    #pragma unroll
    for (int j = 0; j < 8; ++j) { unsigned short hh, ll; split2(xs[j], hh, ll); h[j] = hh; l[j] = ll; }
    *(u16x8*)(hi + i * 8) = h;
    *(u16x8*)(lo + i * 8) = l;
}

// ---------------------------------------------------------------------------
// fp32 -> bf16-hi only (RNE), streaming
// ---------------------------------------------------------------------------
__global__ __launch_bounds__(256) void shi_k(const float* __restrict__ in,
                                             u16* __restrict__ hi, long long n8) {
    long long i = (long long)blockIdx.x * 256 + threadIdx.x;
    if (i >= n8) return;
    const float4* p = (const float4*)in + i * 2;
    float4 a = p[0], b = p[1];
    u16x8 h;
    h[0] = f2bf(a.x); h[1] = f2bf(a.y); h[2] = f2bf(a.z); h[3] = f2bf(a.w);
    h[4] = f2bf(b.x); h[5] = f2bf(b.y); h[6] = f2bf(b.z); h[7] = f2bf(b.w);
    *(u16x8*)(hi + i * 8) = h;
}

// ---------------------------------------------------------------------------
// gemm2b — 128x128-tile split-bf16 MFMA GEMM (NT), 8 waves, dbuf LDS.
// A: hi/lo planes via global_load_lds.
//   BF=0: B fp32 -> REGS -> convert -> ds_write (swizzled)
//   BF=1: B bf16 planes via global_load_lds
// BL=1: B hi+lo (3-term, 32KB buf). BL=0: B hi-only (2-term, 24KB buf).
// AT=1: A k'-tiled planes [kb][row][32]. EPI: 0 fp32, 1 relu(g*sc*x+b).
// FUSE2: grid.z=32, op=z>>4. KS: K-split (BF=0 path: parity base shift).
// ---------------------------------------------------------------------------
template <int BF, int EPI, int FUSE2, int KS, int AT, int BL>
__global__ __launch_bounds__(512, 4) void gemm2b(
    const u16* __restrict__ Ah0, const u16* __restrict__ Al0,
    const u16* __restrict__ Ah1, const u16* __restrict__ Al1,
    long long aB, int lda,
    const void* __restrict__ B0a, const void* __restrict__ B0b,
    const void* __restrict__ B1a, const void* __restrict__ B1b,
    long long bB, int ldb,
    float* __restrict__ C0, float* __restrict__ C1,
    long long cB, long long kB, int ldc,
    int K,
    const float* __restrict__ g0, const float* __restrict__ bb0,
    const float* __restrict__ g1, const float* __restrict__ bb1)
{
    constexpr int BUFB = (BL == 1) ? 32768 : 24576;
    __shared__ __attribute__((aligned(16))) char smem[2][BUFB];

    // bijective XCD-chunk swizzle (nwg % 8 == 0 for all grids used)
    const int gx = gridDim.x, gy = gridDim.y;
    int nwg = gx * gy * gridDim.z;
    int id = blockIdx.x + gx * (blockIdx.y + gy * blockIdx.z);
    int chunk = nwg >> 3;
    int nid = (id & 7) * chunk + (id >> 3);
    int bx = nid % gx;
    int tmp = nid / gx;
    int by = tmp % gy;
    int bz = tmp / gy;

    const int t = threadIdx.x;
    const int n0 = bx * 128, m0 = by * 128;

    int op = 0, batch, kz = 0;
    if constexpr (FUSE2) { op = bz >> 4; batch = bz & 15; }
    else if constexpr (KS > 1) { batch = bz / KS; kz = bz - batch * KS; }
    else { batch = bz; }
    const int koffA = kz * K;

    const u16* Ahp = (op ? Ah1 : Ah0) + (long long)batch * aB + (AT ? 0 : koffA);
    const u16* Alp = (op ? Al1 : Al0) + (long long)batch * aB + (AT ? 0 : koffA);
    const float* Bf = nullptr;
    const u16* Bh = nullptr;
    const u16* Bl = nullptr;
    if constexpr (BF == 0) {
        Bf = (const float*)(op ? B1a : B0a) + (long long)batch * bB;
        // k'-parity base shift (G3); zero when koffA==0
        Bf += ((long long)(koffA >> 10)) * 1024 * ldb + (koffA & 1023);
    } else {
        Bh = (const u16*)(op ? B1a : B0a) + (long long)batch * bB;
        if constexpr (BL == 1) Bl = (const u16*)(op ? B1b : B0b) + (long long)batch * bB;
    }
    float* Cb = ((EPI == 1 && FUSE2) ? (op ? C1 : C0) : C0)
              + (long long)batch * cB + (long long)kz * kB;
    const float* gp = op ? g1 : g0;
    const float* bp = op ? bb1 : bb0;

    // ---- staging coords ----
    const int arow = t >> 2;                          // rows 0..127
    const int aslt = (t & 3) ^ ((t >> 3) & 3);        // inverse-swz source slot
    const int bswz = (t & 3) ^ ((arow >> 1) & 3);     // B ds_write dest slot

    // ---- fragment coords: 8 waves -> wr in {0,1}, wc in {0..3} ----
    const int l = t & 63, w = t >> 6;
    const int wr = w >> 2, wc = w & 3;
    const int rl = l & 15, kq = l >> 4;
    const int fsw = (kq ^ ((rl >> 1) & 3)) * 16;

    f32x4 acc[4][2];
    #pragma unroll
    for (int i = 0; i < 4; ++i)
        #pragma unroll
        for (int j = 0; j < 2; ++j)
            acc[i][j] = (f32x4){0.f, 0.f, 0.f, 0.f};

    float4 rb0, rb1;   // B fp32 stage regs (BF==0)

    auto loadBregs = [&](int k0) {
        if constexpr (BF == 0) {
            const float* p = Bf + (long long)(n0 + arow) * ldb + k0 + (t & 3) * 8;
            rb0 = *(const float4*)p;
            rb1 = *(const float4*)(p + 4);
        }
    };
    auto gstage = [&](int k0, char* sn) {
        if constexpr (AT == 1) {
            long long tb = (long long)((koffA + k0) >> 5) * 8192;
            gload16(Ahp + tb + (m0 + arow) * 32 + aslt * 8, sn + t * 16);
            gload16(Alp + tb + (m0 + arow) * 32 + aslt * 8, sn + 8192 + t * 16);
        } else {
            gload16(Ahp + (long long)(m0 + arow) * lda + k0 + aslt * 8, sn + t * 16);
            gload16(Alp + (long long)(m0 + arow) * lda + k0 + aslt * 8, sn + 8192 + t * 16);
        }
        if constexpr (BF == 1) {
            gload16(Bh + (long long)(n0 + arow) * ldb + k0 + aslt * 8, sn + 16384 + t * 16);
            if constexpr (BL == 1)
                gload16(Bl + (long long)(n0 + arow) * ldb + k0 + aslt * 8, sn + 24576 + t * 16);
        }
    };
    auto splitWriteB = [&](char* sn) {
        if constexpr (BF == 0) {
            float xs[8] = {rb0.x, rb0.y, rb0.z, rb0.w, rb1.x, rb1.y, rb1.z, rb1.w};
            char* base = sn + 16384 + arow * 64 + bswz * 16;
            if constexpr (BL == 1) {
                u16x8 h, lo;
                #pragma unroll
                for (int e = 0; e < 8; ++e) {
                    unsigned short hh, ll; split2(xs[e], hh, ll);
                    h[e] = hh; lo[e] = ll;
                }
                *(u16x8*)(base) = h;
                *(u16x8*)(base + 8192) = lo;
            } else {
                u16x8 h;
                #pragma unroll
                for (int e = 0; e < 8; ++e) h[e] = f2bf(xs[e]);
                *(u16x8*)(base) = h;
            }
        }
    };

    auto readA = [&](const char* sb, bf16x8* fah, bf16x8* fal) {
        #pragma unroll
        for (int i2 = 0; i2 < 4; ++i2) {
            int off = (wr * 64 + i2 * 16 + rl) * 64 + fsw;
            fah[i2] = *(const bf16x8*)(sb + off);
            fal[i2] = *(const bf16x8*)(sb + 8192 + off);
        }
    };
    auto readB = [&](const char* sb, bf16x8* fbh, bf16x8* fbl) {
        #pragma unroll
        for (int j = 0; j < 2; ++j) {
            int off = (wc * 32 + j * 16 + rl) * 64 + fsw;
            fbh[j] = *(const bf16x8*)(sb + 16384 + off);
            if constexpr (BL == 1) fbl[j] = *(const bf16x8*)(sb + 24576 + off);
        }
    };

    const int NIT = K >> 5;

    // ---- prologue ----
    loadBregs(0);
    gstage(0, smem[0]);
    if constexpr (BF == 0) {
        asm volatile("s_waitcnt vmcnt(2)" ::: "memory");   // B regs ready
        splitWriteB(smem[0]);
    }
    asm volatile("s_waitcnt vmcnt(0)" ::: "memory");
    asm volatile("s_waitcnt lgkmcnt(0)" ::: "memory");
    __builtin_amdgcn_s_barrier();

    for (int it = 0; it < NIT; ++it) {
        char* sb = smem[it & 1];
        char* sn = smem[(it + 1) & 1];
        const bool more = (it + 1) < NIT;
        if (more) { loadBregs((it + 1) << 5); gstage((it + 1) << 5, sn); }

        bf16x8 fah[4], fal[4], fbh[2], fbl[2];
        readB(sb, fbh, fbl);
        readA(sb, fah, fal);

        if (more && BF == 0) {
            asm volatile("s_waitcnt vmcnt(2)" ::: "memory");   // B regs in
            splitWriteB(sn);
        }

        __builtin_amdgcn_s_setprio(1);
        #pragma unroll
        for (int i2 = 0; i2 < 4; ++i2)
            #pragma unroll
            for (int j = 0; j < 2; ++j)
                acc[i2][j] = __builtin_amdgcn_mfma_f32_16x16x32_bf16(fal[i2], fbh[j], acc[i2][j], 0, 0, 0);
        if constexpr (BL == 1) {
            #pragma unroll
            for (int i2 = 0; i2 < 4; ++i2)
                #pragma unroll
                for (int j = 0; j < 2; ++j)
                    acc[i2][j] = __builtin_amdgcn_mfma_f32_16x16x32_bf16(fah[i2], fbl[j], acc[i2][j], 0, 0, 0);
        }
        #pragma unroll
        for (int i2 = 0; i2 < 4; ++i2)
            #pragma unroll
            for (int j = 0; j < 2; ++j)
                acc[i2][j] = __builtin_amdgcn_mfma_f32_16x16x32_bf16(fah[i2], fbh[j], acc[i2][j], 0, 0, 0);
        __builtin_amdgcn_s_setprio(0);

        if (more) { asm volatile("s_waitcnt vmcnt(0)" ::: "memory"); }
        asm volatile("s_waitcnt lgkmcnt(0)" ::: "memory");
        __builtin_amdgcn_s_barrier();
    }

    // ---- epilogue ----
    #pragma unroll
    for (int i = 0; i < 4; ++i) {
        #pragma unroll
        for (int r = 0; r < 4; ++r) {
            int row = m0 + wr * 64 + i * 16 + kq * 4 + r;
            float sc = 1.0f, bi = 0.0f;
            if (EPI == 1) { sc = gp[row] * BN_RSQRT; bi = bp[row]; }
            #pragma unroll
            for (int j = 0; j < 2; ++j) {
                int col = n0 + wc * 32 + j * 16 + rl;
                float v = acc[i][j][r];
                if (EPI == 1) v = fmaxf(fmaf(v, sc, bi), 0.0f);
                Cb[(long long)row * ldc + col] = v;
            }
        }
    }
}

// ---------------------------------------------------------------------------
// 128-wide split-bf16 MFMA GEMM (gram + lat2t), plane inputs only
// ---------------------------------------------------------------------------
template <int BN_, int EPI>
__global__ __launch_bounds__(256) void mfma_gemm(
    const void* __restrict__ Ap, const void* __restrict__ Ap2, long long aB, int lda,
    const void* __restrict__ Bp, const void* __restrict__ Bp2, long long bB, int ldb,
    void* __restrict__ Cp, void* __restrict__ Cp2,
    long long cB, int ldc, int K)
{
    constexpr int NJ   = BN_ / 32;
    constexpr int BNB  = BN_ * 64;
    constexpr int BUFB = 16384 + BN_ * 128;
    __shared__ __attribute__((aligned(16))) char smem[2][BUFB];

    const int gx = gridDim.x, gy = gridDim.y;
    int nwg = gx * gy * gridDim.z;
    int id = blockIdx.x + gx * (blockIdx.y + gy * blockIdx.z);
    int chunk = nwg >> 3;
    int nid = (id & 7) * chunk + (id >> 3);
    int bx = nid % gx;
    int tmp = nid / gx;
    int by = tmp % gy;
    int bz = tmp / gy;

    const int t  = threadIdx.x;
    const int n0 = bx * BN_;
    const int m0 = by * 128;

    const int ar = t >> 1, ag = t & 1;
    const int af = (ar >> 1) & 3;
    const int as0 = (2 * ag) ^ af, as1 = (2 * ag + 1) ^ af;
    const bool bact = (BN_ == 128) || (t < 2 * BN_);
    const int br = (t >> 1) & (BN_ - 1), bg = t & 1;
    const int bf = (br >> 1) & 3;
    const int bs0 = (2 * bg) ^ bf, bs1 = (2 * bg + 1) ^ bf;

    const int l  = t & 63, w = t >> 6;
    const int wr = w >> 1, wc = w & 1;
    const int rl = l & 15, kq = l >> 4;
    const int sw = kq ^ ((rl >> 1) & 3);
    const int aoff = (wr * 64 + rl) * 64 + sw * 16;
    const int boff = (wc * (BN_ / 2) + rl) * 64 + sw * 16;

    const u16* Ahp = (const u16*)Ap  + (long long)bz * aB;
    const u16* Alp = (const u16*)Ap2 + (long long)bz * aB;
    const u16* Bhp = (const u16*)Bp  + (long long)bz * bB;
    const u16* Blp = (const u16*)Bp2 + (long long)bz * bB;

    auto loadA = [&](int k0, RegsA& ra) {
        const u16* ph = Ahp + (long long)(m0 + ar) * lda + k0 + ag * 16;
        const u16* pl = Alp + (long long)(m0 + ar) * lda + k0 + ag * 16;
        ra.h[0] = *(const u16x8*)(ph);
        ra.h[1] = *(const u16x8*)(ph + 8);
        ra.l[0] = *(const u16x8*)(pl);
        ra.l[1] = *(const u16x8*)(pl + 8);
    };
    auto loadB = [&](int k0, RegsB& rb) {
        if (!bact) return;
        const u16* ph = Bhp + (long long)(n0 + br) * ldb + k0 + bg * 16;
        const u16* pl = Blp + (long long)(n0 + br) * ldb + k0 + bg * 16;
        rb.h[0] = *(const u16x8*)(ph);
        rb.h[1] = *(const u16x8*)(ph + 8);
        rb.l[0] = *(const u16x8*)(pl);
        rb.l[1] = *(const u16x8*)(pl + 8);
    };
    auto stageWrite = [&](char* sb, RegsA& ra, RegsB& rb) {
        *(u16x8*)(sb + ar * 64 + as0 * 16) = ra.h[0];
        *(u16x8*)(sb + ar * 64 + as1 * 16) = ra.h[1];
        *(u16x8*)(sb + 8192 + ar * 64 + as0 * 16) = ra.l[0];
        *(u16x8*)(sb + 8192 + ar * 64 + as1 * 16) = ra.l[1];
        if (bact) {
            char* sB = sb + 16384;
            *(u16x8*)(sB + br * 64 + bs0 * 16) = rb.h[0];
            *(u16x8*)(sB + br * 64 + bs1 * 16) = rb.h[1];
            *(u16x8*)(sB + BNB + br * 64 + bs0 * 16) = rb.l[0];
            *(u16x8*)(sB + BNB + br * 64 + bs1 * 16) = rb.l[1];
        }
    };

    f32x4 acc[4][NJ];
    #pragma unroll
    for (int i = 0; i < 4; ++i)
        #pragma unroll
        for (int j = 0; j < NJ; ++j)
            acc[i][j] = (f32x4){0.f, 0.f, 0.f, 0.f};

    RegsA a0, a1;
    RegsB b0, b1;
    const int NIT = K >> 5;

    loadA(0, a0); loadB(0, b0);
    stageWrite(smem[0], a0, b0);
    loadA(32, a1); loadB(32, b1);
    asm volatile("s_waitcnt lgkmcnt(0)" ::: "memory");
    __builtin_amdgcn_s_barrier();

    auto step = [&](int it, char* sb, char* sn, RegsA& pa, RegsB& pb,
                    RegsA& qa, RegsB& qb) {
        bf16x8 fah[4], fal[4], fbh[NJ], fbl[NJ];
        #pragma unroll
        for (int i = 0; i < 4; ++i) {
            fah[i] = *(const bf16x8*)(sb + aoff + i * 1024);
            fal[i] = *(const bf16x8*)(sb + 8192 + aoff + i * 1024);
        }
        #pragma unroll
        for (int j = 0; j < NJ; ++j) {
            fbh[j] = *(const bf16x8*)(sb + 16384 + boff + j * 1024);
            fbl[j] = *(const bf16x8*)(sb + 16384 + BNB + boff + j * 1024);
        }
        if (it + 1 < NIT) stageWrite(sn, pa, pb);
        if (it + 2 < NIT) { loadA((it + 2) << 5, qa); loadB((it + 2) << 5, qb); }
        #pragma unroll
        for (int i = 0; i < 4; ++i)
            #pragma unroll
            for (int j = 0; j < NJ; ++j) {
                acc[i][j] = __builtin_amdgcn_mfma_f32_16x16x32_bf16(fal[i], fbh[j], acc[i][j], 0, 0, 0);
                acc[i][j] = __builtin_amdgcn_mfma_f32_16x16x32_bf16(fah[i], fbl[j], acc[i][j], 0, 0, 0);
                acc[i][j] = __builtin_amdgcn_mfma_f32_16x16x32_bf16(fah[i], fbh[j], acc[i][j], 0, 0, 0);
            }
        asm volatile("s_waitcnt lgkmcnt(0)" ::: "memory");
        __builtin_amdgcn_s_barrier();
    };

    for (int it = 0; it < NIT; it += 2) {
        step(it,     smem[0], smem[1], a1, b1, a0, b0);
        step(it + 1, smem[1], smem[0], a0, b0, a1, b1);
    }

    #pragma unroll
    for (int i = 0; i < 4; ++i) {
        #pragma unroll
        for (int r = 0; r < 4; ++r) {
            int row = m0 + wr * 64 + i * 16 + kq * 4 + r;
            #pragma unroll
            for (int j = 0; j < NJ; ++j) {
                int col = n0 + wc * (BN_ / 2) + j * 16 + rl;
                float v = acc[i][j][r];
                if constexpr (EPI == 0) {
                    ((float*)Cp + (long long)bz * cB)[(long long)row * ldc + col] = v;
                } else {
                    unsigned short hh, ll; split2(v, hh, ll);
                    ((u16*)Cp  + (long long)bz * cB)[(long long)row * ldc + col] = hh;
                    ((u16*)Cp2 + (long long)bz * cB)[(long long)row * ldc + col] = ll;
                }
            }
        }
    }
}

// ---------------------------------------------------------------------------
// Row L2-norm over C of Yv[B][D][C] fp32 -> K'-TILED split planes in T:
// T[b] = [hi: kb(0..63)][d][32] | [lo: same]  (k' = (c&1)*1024 + (c>>1))
// ---------------------------------------------------------------------------
__global__ __launch_bounds__(256) void rownorm_split_tiled_k(const float* __restrict__ Y,
                                                             u16* __restrict__ T) {
    int d = blockIdx.x, b = blockIdx.y, t = threadIdx.x;
    const float* row = Y + ((long long)b * DD + d) * CC;
    float4 v0 = ((const float4*)row)[2 * t];
    float4 v1 = ((const float4*)row)[2 * t + 1];
    float s = v0.x * v0.x + v0.y * v0.y + v0.z * v0.z + v0.w * v0.w
            + v1.x * v1.x + v1.y * v1.y + v1.z * v1.z + v1.w * v1.w;
    for (int off = 32; off > 0; off >>= 1) s += __shfl_down(s, off, 64);
    __shared__ float wsum[4];
    __shared__ float ivs;
    int lane = t & 63, w = t >> 6;
    if (lane == 0) wsum[w] = s;
    __syncthreads();
    if (t == 0) ivs = 1.0f / fmaxf(sqrtf(wsum[0] + wsum[1] + wsum[2] + wsum[3]), 1e-12f);
    __syncthreads();
    float iv = ivs;
    float xs[8] = {v0.x * iv, v0.y * iv, v0.z * iv, v0.w * iv,
                   v1.x * iv, v1.y * iv, v1.z * iv, v1.w * iv};
    u16x4 he, ho, le, lo4;
    #pragma unroll
    for (int j = 0; j < 4; ++j) {
        unsigned short hh, ll;
        split2(xs[2 * j], hh, ll);       he[j] = hh; le[j] = ll;
        split2(xs[2 * j + 1], hh, ll);   ho[j] = hh; lo4[j] = ll;
    }
    u16* Tb = T + (long long)b * 1048576;
    int kk  = 4 * (t & 7);
    long long oE = ((long long)(t >> 3) * 256 + d) * 32 + kk;
    long long oO = ((long long)(32 + (t >> 3)) * 256 + d) * 32 + kk;
    *(u16x4*)(Tb + oE) = he;
    *(u16x4*)(Tb + oO) = ho;
    *(u16x4*)(Tb + 524288 + oE) = le;
    *(u16x4*)(Tb + 524288 + oO) = lo4;
}

// ---------------------------------------------------------------------------
// FUSED column-norm + transpose + split:
// Yl[B][D=256][C] -> Ylt planes [B][C][D] scaled by 1/||col||_D.
// ---------------------------------------------------------------------------
__global__ __launch_bounds__(256) void transnorm_k(const float* __restrict__ Yl,
                                                   u16* __restrict__ hi, u16* __restrict__ lo) {
    __shared__ float tile[256][33];
    __shared__ float part[8][33];
    __shared__ float invn[32];
    int c0 = blockIdx.x * 32, b = blockIdx.y;
    int t = threadIdx.x;
    int tx = t & 31, ty = t >> 5;
    const float* base = Yl + (long long)b * DD * CC + c0;
    for (int d = ty; d < 256; d += 8)
        tile[d][tx] = base[(long long)d * CC + tx];
    __syncthreads();
    float s = 0.0f;
    #pragma unroll
    for (int dd = 0; dd < 32; ++dd) {
        float v = tile[ty * 32 + dd][tx];
        s += v * v;
    }
    part[ty][tx] = s;
    __syncthreads();
    if (ty == 0) {
        float tot = part[0][tx] + part[1][tx] + part[2][tx] + part[3][tx]
                  + part[4][tx] + part[5][tx] + part[6][tx] + part[7][tx];
        invn[tx] = 1.0f / fmaxf(sqrtf(tot), 1e-12f);
    }
    __syncthreads();
    long long ob = (long long)b * DD * CC;
    #pragma unroll 4
    for (int i = 0; i < 32; ++i) {
        float v = tile[t][i] * invn[i];
        unsigned short hh, ll; split2(v, hh, ll);
        long long o = ob + (long long)(c0 + i) * DD + t;
        hi[o] = hh; lo[o] = ll;
    }
}

// ---------------------------------------------------------------------------
// Sum 2 K-split parts of latent [B][D][HW] -> split planes + transposed planes
// ---------------------------------------------------------------------------
__global__ __launch_bounds__(256) void latreduce_k(const float* __restrict__ parts,
                                                   u16* __restrict__ hi, u16* __restrict__ lo,
                                                   u16* __restrict__ thi, u16* __restrict__ tlo) {
    __shared__ float tile[32][33];
    int h0 = blockIdx.x * 32, d0 = blockIdx.y * 32, b = blockIdx.z;
    const long long sL = (long long)DD * HWW;
    const long long ps = (long long)BB * sL;
    const float* base = parts + (long long)b * sL;
    int tx = threadIdx.x & 31, ty = threadIdx.x >> 5;
    for (int i = ty; i < 32; i += 8) {
        long long o = (long long)(d0 + i) * HWW + h0 + tx;
        float s = base[o] + base[o + ps];
        tile[i][tx] = s;
        unsigned short hh, ll; split2(s, hh, ll);
        long long od = (long long)b * sL + o;
        hi[od] = hh; lo[od] = ll;
    }
    __syncthreads();
    for (int i = ty; i < 32; i += 8) {
        float v = tile[tx][i];
        unsigned short hh, ll; split2(v, hh, ll);
        long long ot = (long long)b * sL + (long long)(h0 + i) * DD + d0 + tx;
        thi[ot] = hh; tlo[ot] = ll;
    }
}

// ---------------------------------------------------------------------------
__global__ __launch_bounds__(256) void latnorm_k(const float* __restrict__ G,
                                                 float* __restrict__ rs) {
    int i = blockIdx.x * 256 + threadIdx.x;
    int b = i >> 8, d = i & 255;
    float v = G[((long long)b * DD + d) * DD + d];
    rs[i] = 1.0f / fmaxf(sqrtf(v), 1e-12f);
}

// softmax over gram rows -> aff hi/lo planes
__global__ __launch_bounds__(256) void softmax_k(const float* __restrict__ G,
                                                 const float* __restrict__ rs,
                                                 u16* __restrict__ affHi,
                                                 u16* __restrict__ affLo) {
    int d = blockIdx.x, b = blockIdx.y;
    const float* row = G + ((long long)b * DD + d) * DD;
    const float* rsb = rs + (long long)b * DD;
    int t = threadIdx.x;
    float lg = row[t] * rsb[d] * rsb[t];

    float m = lg;
    for (int off = 32; off > 0; off >>= 1) m = fmaxf(m, __shfl_down(m, off, 64));
    __shared__ float wsm[4];
    __shared__ float bm, bs;
    int lane = t & 63, w = t >> 6;
    if (lane == 0) wsm[w] = m;
    __syncthreads();
    if (t == 0) bm = fmaxf(fmaxf(wsm[0], wsm[1]), fmaxf(wsm[2], wsm[3]));
    __syncthreads();
    float e = expf(lg - bm);
    float s = e;
    for (int off = 32; off > 0; off >>= 1) s += __shfl_down(s, off, 64);
    if (lane == 0) wsm[w] = s;
    __syncthreads();
    if (t == 0) bs = wsm[0] + wsm[1] + wsm[2] + wsm[3];
    __syncthreads();
    float v = e / bs;
    unsigned short hh, ll; split2(v, hh, ll);
    long long o = ((long long)b * DD + d) * DD + t;
    affHi[o] = hh; affLo[o] = ll;
}

// ---------------------------------------------------------------------------
extern "C" void kernel_launch(void* const* d_in, const int* in_sizes, int n_in,
                              void* d_out, int out_size, void* d_ws, size_t ws_size,
                              hipStream_t stream) {
    const float* v2l   = (const float*)d_in[0];
    const float* l2v   = (const float*)d_in[1];
    const float* w_v2l = (const float*)d_in[2];
    const float* g_v2l = (const float*)d_in[3];
    const float* b_v2l = (const float*)d_in[4];
    const float* w_l2v = (const float*)d_in[5];
    const float* g_l2v = (const float*)d_in[6];
    const float* b_l2v = (const float*)d_in[7];
    float* out = (float*)d_out;

    // d_out scratch (128MB), lifetime-ordered (sizes in BYTES):
    //   v2lH [0,64M): 33.5M bf16 elems, read by G1 (dead after G1+G2)
    //   l2vH [64,128M): read by G2 (dead after G1+G2)
    //   YvT  [64,96M): rownorm output, written AFTER G1+G2 (over dead l2vH)
    u16* v2lH = (u16*)d_out;
    u16* l2vH = (u16*)((char*)d_out + 67108864);
    u16* YvT  = (u16*)((char*)d_out + 67108864);

    char* W = (char*)d_ws;
    float* Yv     = (float*)(W + 0);            // 32MB (dead after rownorm)
    float* Yl     = (float*)(W + 33554432);     // 32MB (dead after transnorm)
    float* latPart= (float*)(W + 0);            // 64MB, overwrites Yv+Yl at G3
    u16*   YltHi  = (u16*)(W + 67108864);       // 16MB
    u16*   YltLo  = (u16*)(W + 83886080);       // 16MB
    u16*   latHi  = (u16*)(W + 100663296);      //  8MB
    u16*   latLo  = (u16*)(W + 109051904);      //  8MB
    u16*   latTHi = (u16*)(W + 117440512);      //  8MB
    u16*   latTLo = (u16*)(W + 125829120);      //  8MB
    u16*   l2tHi  = (u16*)(W + 134217728);      //  8MB
    u16*   l2tLo  = (u16*)(W + 142606336);      //  8MB
    float* gram   = (float*)(W + 150994944);    //  4MB
    float* rs     = (float*)(W + 155189248);
    u16*   affHi  = (u16*)(W + 155336704);      //  2MB
    u16*   affLo  = (u16*)(W + 157433856);      //  2MB
    u16*   WvHi   = (u16*)(W + 159531008);      //  512KB each
    u16*   WvLo   = WvHi + 262144;
    u16*   WlHi   = WvLo + 262144;
    u16*   WlLo   = WlHi + 262144;

    const long long sY   = (long long)DD * CC;     // 524288
    const long long sL   = (long long)DD * HWW;    // 262144
    const long long sG   = (long long)DD * DD;     // 65536
    const long long sX   = (long long)CC * HWW;    // 2097152

    // weights -> hi/lo planes; inputs -> hi-only planes (for G1+G2 B)
    split_k<<<128, 256, 0, stream>>>(w_v2l, WvHi, WvLo, 32768);
    split_k<<<128, 256, 0, stream>>>(w_l2v, WlHi, WlLo, 32768);
    shi_k<<<16384, 256, 0, stream>>>(v2l, v2lH, 4194304);
    shi_k<<<16384, 256, 0, stream>>>(l2v, l2vH, 4194304);

    // G1+G2 fused (B planes via gload, 2-term): Yv/Yl = relu(sc*(W.X^T)+b)
    gemm2b<1, 1, 1, 1, 0, 0><<<dim3(CC / 128, DD / 128, 32), 512, 0, stream>>>(
        WvHi, WvLo, WlHi, WlLo, 0, HWW,
        v2lH, nullptr, l2vH, nullptr, sX, HWW,
        Yv, Yl, sY, 0, CC, HWW,
        g_v2l, b_v2l, g_l2v, b_l2v);

    rownorm_split_tiled_k<<<dim3(DD, BB), 256, 0, stream>>>(Yv, YvT);
    transnorm_k<<<dim3(CC / 32, BB), 256, 0, stream>>>(Yl, YltHi, YltLo);

    // G3 (K-split x2, tiled A, fp32-B reg-staged, 2-term) — R13 path.
    // B = original v2l fp32 input; latPart over dead Yv/Yl in d_ws.
    gemm2b<0, 0, 0, 2, 1, 0><<<dim3(HWW / 128, DD / 128, 32), 512, 0, stream>>>(
        YvT, YvT + 524288, nullptr, nullptr, 1048576, 32,
        v2l, nullptr, nullptr, nullptr, sX, HWW,
        latPart, nullptr, sL, (long long)BB * sL, HWW, 1024,
        nullptr, nullptr, nullptr, nullptr);

    latreduce_k<<<dim3(HWW / 32, DD / 32, BB), 256, 0, stream>>>(
        latPart, latHi, latLo, latTHi, latTLo);

    // gram = latent . latent^T  (plane MFMA, fp32 out)
    mfma_gemm<64, 0><<<dim3(4, 2, BB), 256, 0, stream>>>(
        latHi, latLo, sL, HWW, latHi, latLo, sL, HWW,
        gram, nullptr, sG, DD, HWW);

    latnorm_k<<<dim3(BB * DD / 256), 256, 0, stream>>>(gram, rs);
    softmax_k<<<dim3(DD, BB), 256, 0, stream>>>(gram, rs, affHi, affLo);

    // lat2t = latentT . aff^T  [HW,D] -> planes
    mfma_gemm<128, 2><<<dim3(2, 8, BB), 256, 0, stream>>>(
        latTHi, latTLo, sL, DD, affHi, affLo, sG, DD,
        l2tHi, l2tLo, sL, DD, DD);

    // G6 (B planes via gload, full 3-term, final output): out = Ylt . l2t^T
    gemm2b<1, 0, 0, 1, 0, 1><<<dim3(HWW / 128, CC / 128, BB), 512, 0, stream>>>(
        YltHi, YltLo, nullptr, nullptr, sY, DD,
        l2tHi, l2tLo, nullptr, nullptr, sL, DD,
        out, nullptr, sX, 0, HWW, DD,
        nullptr, nullptr, nullptr, nullptr);
}

// Round 19
// 325.759 us; speedup vs baseline: 1.1514x; 1.1514x over previous
//
#include <hip/hip_runtime.h>
#include <hip/hip_bf16.h>

#define BB 16
#define CC 2048
#define HWW 1024
#define DD 256
#define BN_RSQRT 0.9999950000374997f

typedef short bf16x8 __attribute__((ext_vector_type(8)));
typedef float f32x4 __attribute__((ext_vector_type(4)));
typedef unsigned short u16x8 __attribute__((ext_vector_type(8)));
typedef unsigned short u16x4 __attribute__((ext_vector_type(4)));
typedef unsigned short u16;

typedef __attribute__((address_space(1))) const unsigned GU;
typedef __attribute__((address_space(3))) unsigned LU;
__device__ __forceinline__ void gload16(const void* g, void* l) {
    __builtin_amdgcn_global_load_lds((GU*)g, (LU*)l, 16, 0, 0);
}

// ---- bf16 split helpers (RNE) ----
__device__ __forceinline__ unsigned short f2bf(float x) {
    unsigned u = __builtin_bit_cast(unsigned, x);
    unsigned r = u + 0x7FFFu + ((u >> 16) & 1u);
    return (unsigned short)(r >> 16);
}
__device__ __forceinline__ float bf2f(unsigned short h) {
    unsigned u = ((unsigned)h) << 16;
    return __builtin_bit_cast(float, u);
}
__device__ __forceinline__ void split2(float x, unsigned short& hi, unsigned short& lo) {
    hi = f2bf(x);
    lo = f2bf(x - bf2f(hi));
}

struct RegsA { u16x8 h[2]; u16x8 l[2]; };
struct RegsB { u16x8 h[2]; u16x8 l[2]; };

// ---------------------------------------------------------------------------
// split fp32 -> hi/lo bf16 planes (weights only)
// ---------------------------------------------------------------------------
__global__ __launch_bounds__(256) void split_k(const float* __restrict__ in,
                                               u16* __restrict__ hi, u16* __restrict__ lo,
                                               long long n8) {
    long long i = (long long)blockIdx.x * 256 + threadIdx.x;
    if (i >= n8) return;
    const float4* p = (const float4*)in + i * 2;
    float4 a = p[0], b = p[1];
    float xs[8] = {a.x, a.y, a.z, a.w, b.x, b.y, b.z, b.w};
    u16x8 h, l;
    #pragma unroll
    for (int j = 0; j < 8; ++j) { unsigned short hh, ll; split2(xs[j], hh, ll); h[j] = hh; l[j] = ll; }
    *(u16x8*)(hi + i * 8) = h;
    *(u16x8*)(lo + i * 8) = l;
}

// ---------------------------------------------------------------------------
// gemm2b — 128x128-tile split-bf16 MFMA GEMM (NT), 8 waves, dbuf LDS.
// A: hi/lo planes via global_load_lds.
//   BF=0: B fp32 -> REGS -> convert -> ds_write (swizzled)
//   BF=1: B bf16 planes via global_load_lds
// BL=1: B hi+lo (3-term, 32KB buf). BL=0: B hi-only (2-term, 24KB buf).
// AT=1: A k'-tiled planes [kb][row][32]. EPI: 0 fp32, 1 relu(g*sc*x+b).
// FUSE2: grid.z=32, op=z>>4. KS: K-split (BF=0 path: parity base shift).
// ---------------------------------------------------------------------------
template <int BF, int EPI, int FUSE2, int KS, int AT, int BL>
__global__ __launch_bounds__(512, 4) void gemm2b(
    const u16* __restrict__ Ah0, const u16* __restrict__ Al0,
    const u16* __restrict__ Ah1, const u16* __restrict__ Al1,
    long long aB, int lda,
    const void* __restrict__ B0a, const void* __restrict__ B0b,
    const void* __restrict__ B1a, const void* __restrict__ B1b,
    long long bB, int ldb,
    float* __restrict__ C0, float* __restrict__ C1,
    long long cB, long long kB, int ldc,
    int K,
    const float* __restrict__ g0, const float* __restrict__ bb0,
    const float* __restrict__ g1, const float* __restrict__ bb1)
{
    constexpr int BUFB = (BL == 1) ? 32768 : 24576;
    __shared__ __attribute__((aligned(16))) char smem[2][BUFB];

    // bijective XCD-chunk swizzle (nwg % 8 == 0 for all grids used)
    const int gx = gridDim.x, gy = gridDim.y;
    int nwg = gx * gy * gridDim.z;
    int id = blockIdx.x + gx * (blockIdx.y + gy * blockIdx.z);
    int chunk = nwg >> 3;
    int nid = (id & 7) * chunk + (id >> 3);
    int bx = nid % gx;
    int tmp = nid / gx;
    int by = tmp % gy;
    int bz = tmp / gy;

    const int t = threadIdx.x;
    const int n0 = bx * 128, m0 = by * 128;

    int op = 0, batch, kz = 0;
    if constexpr (FUSE2) { op = bz >> 4; batch = bz & 15; }
    else if constexpr (KS > 1) { batch = bz / KS; kz = bz - batch * KS; }
    else { batch = bz; }
    const int koffA = kz * K;

    const u16* Ahp = (op ? Ah1 : Ah0) + (long long)batch * aB + (AT ? 0 : koffA);
    const u16* Alp = (op ? Al1 : Al0) + (long long)batch * aB + (AT ? 0 : koffA);
    const float* Bf = nullptr;
    const u16* Bh = nullptr;
    const u16* Bl = nullptr;
    if constexpr (BF == 0) {
        Bf = (const float*)(op ? B1a : B0a) + (long long)batch * bB;
        // k'-parity base shift (G3); zero when koffA==0
        Bf += ((long long)(koffA >> 10)) * 1024 * ldb + (koffA & 1023);
    } else {
        Bh = (const u16*)(op ? B1a : B0a) + (long long)batch * bB;
        if constexpr (BL == 1) Bl = (const u16*)(op ? B1b : B0b) + (long long)batch * bB;
    }
    float* Cb = ((EPI == 1 && FUSE2) ? (op ? C1 : C0) : C0)
              + (long long)batch * cB + (long long)kz * kB;
    const float* gp = op ? g1 : g0;
    const float* bp = op ? bb1 : bb0;

    // ---- staging coords ----
    const int arow = t >> 2;                          // rows 0..127
    const int aslt = (t & 3) ^ ((t >> 3) & 3);        // inverse-swz source slot
    const int bswz = (t & 3) ^ ((arow >> 1) & 3);     // B ds_write dest slot

    // ---- fragment coords: 8 waves -> wr in {0,1}, wc in {0..3} ----
    const int l = t & 63, w = t >> 6;
    const int wr = w >> 2, wc = w & 3;
    const int rl = l & 15, kq = l >> 4;
    const int fsw = (kq ^ ((rl >> 1) & 3)) * 16;

    f32x4 acc[4][2];
    #pragma unroll
    for (int i = 0; i < 4; ++i)
        #pragma unroll
        for (int j = 0; j < 2; ++j)
            acc[i][j] = (f32x4){0.f, 0.f, 0.f, 0.f};

    float4 rb0, rb1;   // B fp32 stage regs (BF==0)

    auto loadBregs = [&](int k0) {
        if constexpr (BF == 0) {
            const float* p = Bf + (long long)(n0 + arow) * ldb + k0 + (t & 3) * 8;
            rb0 = *(const float4*)p;
            rb1 = *(const float4*)(p + 4);
        }
    };
    auto gstage = [&](int k0, char* sn) {
        if constexpr (AT == 1) {
            long long tb = (long long)((koffA + k0) >> 5) * 8192;
            gload16(Ahp + tb + (m0 + arow) * 32 + aslt * 8, sn + t * 16);
            gload16(Alp + tb + (m0 + arow) * 32 + aslt * 8, sn + 8192 + t * 16);
        } else {
            gload16(Ahp + (long long)(m0 + arow) * lda + k0 + aslt * 8, sn + t * 16);
            gload16(Alp + (long long)(m0 + arow) * lda + k0 + aslt * 8, sn + 8192 + t * 16);
        }
        if constexpr (BF == 1) {
            gload16(Bh + (long long)(n0 + arow) * ldb + k0 + aslt * 8, sn + 16384 + t * 16);
            if constexpr (BL == 1)
                gload16(Bl + (long long)(n0 + arow) * ldb + k0 + aslt * 8, sn + 24576 + t * 16);
        }
    };
    auto splitWriteB = [&](char* sn) {
        if constexpr (BF == 0) {
            float xs[8] = {rb0.x, rb0.y, rb0.z, rb0.w, rb1.x, rb1.y, rb1.z, rb1.w};
            char* base = sn + 16384 + arow * 64 + bswz * 16;
            if constexpr (BL == 1) {
                u16x8 h, lo;
                #pragma unroll
                for (int e = 0; e < 8; ++e) {
                    unsigned short hh, ll; split2(xs[e], hh, ll);
                    h[e] = hh; lo[e] = ll;
                }
                *(u16x8*)(base) = h;
                *(u16x8*)(base + 8192) = lo;
            } else {
                u16x8 h;
                #pragma unroll
                for (int e = 0; e < 8; ++e) h[e] = f2bf(xs[e]);
                *(u16x8*)(base) = h;
            }
        }
    };

    auto readA = [&](const char* sb, bf16x8* fah, bf16x8* fal) {
        #pragma unroll
        for (int i2 = 0; i2 < 4; ++i2) {
            int off = (wr * 64 + i2 * 16 + rl) * 64 + fsw;
            fah[i2] = *(const bf16x8*)(sb + off);
            fal[i2] = *(const bf16x8*)(sb + 8192 + off);
        }
    };
    auto readB = [&](const char* sb, bf16x8* fbh, bf16x8* fbl) {
        #pragma unroll
        for (int j = 0; j < 2; ++j) {
            int off = (wc * 32 + j * 16 + rl) * 64 + fsw;
            fbh[j] = *(const bf16x8*)(sb + 16384 + off);
            if constexpr (BL == 1) fbl[j] = *(const bf16x8*)(sb + 24576 + off);
        }
    };

    const int NIT = K >> 5;

    // ---- prologue ----
    loadBregs(0);
    gstage(0, smem[0]);
    if constexpr (BF == 0) {
        asm volatile("s_waitcnt vmcnt(2)" ::: "memory");   // B regs ready
        splitWriteB(smem[0]);
    }
    asm volatile("s_waitcnt vmcnt(0)" ::: "memory");
    asm volatile("s_waitcnt lgkmcnt(0)" ::: "memory");
    __builtin_amdgcn_s_barrier();

    for (int it = 0; it < NIT; ++it) {
        char* sb = smem[it & 1];
        char* sn = smem[(it + 1) & 1];
        const bool more = (it + 1) < NIT;
        if (more) { loadBregs((it + 1) << 5); gstage((it + 1) << 5, sn); }

        bf16x8 fah[4], fal[4], fbh[2], fbl[2];
        readB(sb, fbh, fbl);
        readA(sb, fah, fal);

        if (more && BF == 0) {
            asm volatile("s_waitcnt vmcnt(2)" ::: "memory");   // B regs in
            splitWriteB(sn);
        }

        __builtin_amdgcn_s_setprio(1);
        #pragma unroll
        for (int i2 = 0; i2 < 4; ++i2)
            #pragma unroll
            for (int j = 0; j < 2; ++j)
                acc[i2][j] = __builtin_amdgcn_mfma_f32_16x16x32_bf16(fal[i2], fbh[j], acc[i2][j], 0, 0, 0);
        if constexpr (BL == 1) {
            #pragma unroll
            for (int i2 = 0; i2 < 4; ++i2)
                #pragma unroll
                for (int j = 0; j < 2; ++j)
                    acc[i2][j] = __builtin_amdgcn_mfma_f32_16x16x32_bf16(fah[i2], fbl[j], acc[i2][j], 0, 0, 0);
        }
        #pragma unroll
        for (int i2 = 0; i2 < 4; ++i2)
            #pragma unroll
            for (int j = 0; j < 2; ++j)
                acc[i2][j] = __builtin_amdgcn_mfma_f32_16x16x32_bf16(fah[i2], fbh[j], acc[i2][j], 0, 0, 0);
        __builtin_amdgcn_s_setprio(0);

        if (more) { asm volatile("s_waitcnt vmcnt(0)" ::: "memory"); }
        asm volatile("s_waitcnt lgkmcnt(0)" ::: "memory");
        __builtin_amdgcn_s_barrier();
    }

    // ---- epilogue ----
    #pragma unroll
    for (int i = 0; i < 4; ++i) {
        #pragma unroll
        for (int r = 0; r < 4; ++r) {
            int row = m0 + wr * 64 + i * 16 + kq * 4 + r;
            float sc = 1.0f, bi = 0.0f;
            if (EPI == 1) { sc = gp[row] * BN_RSQRT; bi = bp[row]; }
            #pragma unroll
            for (int j = 0; j < 2; ++j) {
                int col = n0 + wc * 32 + j * 16 + rl;
                float v = acc[i][j][r];
                if (EPI == 1) v = fmaxf(fmaf(v, sc, bi), 0.0f);
                Cb[(long long)row * ldc + col] = v;
            }
        }
    }
}

// ---------------------------------------------------------------------------
// 128-wide split-bf16 MFMA GEMM (gram + lat2t), plane inputs only
// ---------------------------------------------------------------------------
template <int BN_, int EPI>
__global__ __launch_bounds__(256) void mfma_gemm(
    const void* __restrict__ Ap, const void* __restrict__ Ap2, long long aB, int lda,
    const void* __restrict__ Bp, const void* __restrict__ Bp2, long long bB, int ldb,
    void* __restrict__ Cp, void* __restrict__ Cp2,
    long long cB, int ldc, int K)
{
    constexpr int NJ   = BN_ / 32;
    constexpr int BNB  = BN_ * 64;
    constexpr int BUFB = 16384 + BN_ * 128;
    __shared__ __attribute__((aligned(16))) char smem[2][BUFB];

    const int gx = gridDim.x, gy = gridDim.y;
    int nwg = gx * gy * gridDim.z;
    int id = blockIdx.x + gx * (blockIdx.y + gy * blockIdx.z);
    int chunk = nwg >> 3;
    int nid = (id & 7) * chunk + (id >> 3);
    int bx = nid % gx;
    int tmp = nid / gx;
    int by = tmp % gy;
    int bz = tmp / gy;

    const int t  = threadIdx.x;
    const int n0 = bx * BN_;
    const int m0 = by * 128;

    const int ar = t >> 1, ag = t & 1;
    const int af = (ar >> 1) & 3;
    const int as0 = (2 * ag) ^ af, as1 = (2 * ag + 1) ^ af;
    const bool bact = (BN_ == 128) || (t < 2 * BN_);
    const int br = (t >> 1) & (BN_ - 1), bg = t & 1;
    const int bf = (br >> 1) & 3;
    const int bs0 = (2 * bg) ^ bf, bs1 = (2 * bg + 1) ^ bf;

    const int l  = t & 63, w = t >> 6;
    const int wr = w >> 1, wc = w & 1;
    const int rl = l & 15, kq = l >> 4;
    const int sw = kq ^ ((rl >> 1) & 3);
    const int aoff = (wr * 64 + rl) * 64 + sw * 16;
    const int boff = (wc * (BN_ / 2) + rl) * 64 + sw * 16;

    const u16* Ahp = (const u16*)Ap  + (long long)bz * aB;
    const u16* Alp = (const u16*)Ap2 + (long long)bz * aB;
    const u16* Bhp = (const u16*)Bp  + (long long)bz * bB;
    const u16* Blp = (const u16*)Bp2 + (long long)bz * bB;

    auto loadA = [&](int k0, RegsA& ra) {
        const u16* ph = Ahp + (long long)(m0 + ar) * lda + k0 + ag * 16;
        const u16* pl = Alp + (long long)(m0 + ar) * lda + k0 + ag * 16;
        ra.h[0] = *(const u16x8*)(ph);
        ra.h[1] = *(const u16x8*)(ph + 8);
        ra.l[0] = *(const u16x8*)(pl);
        ra.l[1] = *(const u16x8*)(pl + 8);
    };
    auto loadB = [&](int k0, RegsB& rb) {
        if (!bact) return;
        const u16* ph = Bhp + (long long)(n0 + br) * ldb + k0 + bg * 16;
        const u16* pl = Blp + (long long)(n0 + br) * ldb + k0 + bg * 16;
        rb.h[0] = *(const u16x8*)(ph);
        rb.h[1] = *(const u16x8*)(ph + 8);
        rb.l[0] = *(const u16x8*)(pl);
        rb.l[1] = *(const u16x8*)(pl + 8);
    };
    auto stageWrite = [&](char* sb, RegsA& ra, RegsB& rb) {
        *(u16x8*)(sb + ar * 64 + as0 * 16) = ra.h[0];
        *(u16x8*)(sb + ar * 64 + as1 * 16) = ra.h[1];
        *(u16x8*)(sb + 8192 + ar * 64 + as0 * 16) = ra.l[0];
        *(u16x8*)(sb + 8192 + ar * 64 + as1 * 16) = ra.l[1];
        if (bact) {
            char* sB = sb + 16384;
            *(u16x8*)(sB + br * 64 + bs0 * 16) = rb.h[0];
            *(u16x8*)(sB + br * 64 + bs1 * 16) = rb.h[1];
            *(u16x8*)(sB + BNB + br * 64 + bs0 * 16) = rb.l[0];
            *(u16x8*)(sB + BNB + br * 64 + bs1 * 16) = rb.l[1];
        }
    };

    f32x4 acc[4][NJ];
    #pragma unroll
    for (int i = 0; i < 4; ++i)
        #pragma unroll
        for (int j = 0; j < NJ; ++j)
            acc[i][j] = (f32x4){0.f, 0.f, 0.f, 0.f};

    RegsA a0, a1;
    RegsB b0, b1;
    const int NIT = K >> 5;

    loadA(0, a0); loadB(0, b0);
    stageWrite(smem[0], a0, b0);
    loadA(32, a1); loadB(32, b1);
    asm volatile("s_waitcnt lgkmcnt(0)" ::: "memory");
    __builtin_amdgcn_s_barrier();

    auto step = [&](int it, char* sb, char* sn, RegsA& pa, RegsB& pb,
                    RegsA& qa, RegsB& qb) {
        bf16x8 fah[4], fal[4], fbh[NJ], fbl[NJ];
        #pragma unroll
        for (int i = 0; i < 4; ++i) {
            fah[i] = *(const bf16x8*)(sb + aoff + i * 1024);
            fal[i] = *(const bf16x8*)(sb + 8192 + aoff + i * 1024);
        }
        #pragma unroll
        for (int j = 0; j < NJ; ++j) {
            fbh[j] = *(const bf16x8*)(sb + 16384 + boff + j * 1024);
            fbl[j] = *(const bf16x8*)(sb + 16384 + BNB + boff + j * 1024);
        }
        if (it + 1 < NIT) stageWrite(sn, pa, pb);
        if (it + 2 < NIT) { loadA((it + 2) << 5, qa); loadB((it + 2) << 5, qb); }
        #pragma unroll
        for (int i = 0; i < 4; ++i)
            #pragma unroll
            for (int j = 0; j < NJ; ++j) {
                acc[i][j] = __builtin_amdgcn_mfma_f32_16x16x32_bf16(fal[i], fbh[j], acc[i][j], 0, 0, 0);
                acc[i][j] = __builtin_amdgcn_mfma_f32_16x16x32_bf16(fah[i], fbl[j], acc[i][j], 0, 0, 0);
                acc[i][j] = __builtin_amdgcn_mfma_f32_16x16x32_bf16(fah[i], fbh[j], acc[i][j], 0, 0, 0);
            }
        asm volatile("s_waitcnt lgkmcnt(0)" ::: "memory");
        __builtin_amdgcn_s_barrier();
    };

    for (int it = 0; it < NIT; it += 2) {
        step(it,     smem[0], smem[1], a1, b1, a0, b0);
        step(it + 1, smem[1], smem[0], a0, b0, a1, b1);
    }

    #pragma unroll
    for (int i = 0; i < 4; ++i) {
        #pragma unroll
        for (int r = 0; r < 4; ++r) {
            int row = m0 + wr * 64 + i * 16 + kq * 4 + r;
            #pragma unroll
            for (int j = 0; j < NJ; ++j) {
                int col = n0 + wc * (BN_ / 2) + j * 16 + rl;
                float v = acc[i][j][r];
                if constexpr (EPI == 0) {
                    ((float*)Cp + (long long)bz * cB)[(long long)row * ldc + col] = v;
                } else {
                    unsigned short hh, ll; split2(v, hh, ll);
                    ((u16*)Cp  + (long long)bz * cB)[(long long)row * ldc + col] = hh;
                    ((u16*)Cp2 + (long long)bz * cB)[(long long)row * ldc + col] = ll;
                }
            }
        }
    }
}

// ---------------------------------------------------------------------------
// Row L2-norm over C of Yv[B][D][C] fp32 -> K'-TILED split planes in T:
// T[b] = [hi: kb(0..63)][d][32] | [lo: same]  (k' = (c&1)*1024 + (c>>1))
// ---------------------------------------------------------------------------
__global__ __launch_bounds__(256) void rownorm_split_tiled_k(const float* __restrict__ Y,
                                                             u16* __restrict__ T) {
    int d = blockIdx.x, b = blockIdx.y, t = threadIdx.x;
    const float* row = Y + ((long long)b * DD + d) * CC;
    float4 v0 = ((const float4*)row)[2 * t];
    float4 v1 = ((const float4*)row)[2 * t + 1];
    float s = v0.x * v0.x + v0.y * v0.y + v0.z * v0.z + v0.w * v0.w
            + v1.x * v1.x + v1.y * v1.y + v1.z * v1.z + v1.w * v1.w;
    for (int off = 32; off > 0; off >>= 1) s += __shfl_down(s, off, 64);
    __shared__ float wsum[4];
    __shared__ float ivs;
    int lane = t & 63, w = t >> 6;
    if (lane == 0) wsum[w] = s;
    __syncthreads();
    if (t == 0) ivs = 1.0f / fmaxf(sqrtf(wsum[0] + wsum[1] + wsum[2] + wsum[3]), 1e-12f);
    __syncthreads();
    float iv = ivs;
    float xs[8] = {v0.x * iv, v0.y * iv, v0.z * iv, v0.w * iv,
                   v1.x * iv, v1.y * iv, v1.z * iv, v1.w * iv};
    u16x4 he, ho, le, lo4;
    #pragma unroll
    for (int j = 0; j < 4; ++j) {
        unsigned short hh, ll;
        split2(xs[2 * j], hh, ll);       he[j] = hh; le[j] = ll;
        split2(xs[2 * j + 1], hh, ll);   ho[j] = hh; lo4[j] = ll;
    }
    u16* Tb = T + (long long)b * 1048576;
    int kk  = 4 * (t & 7);
    long long oE = ((long long)(t >> 3) * 256 + d) * 32 + kk;
    long long oO = ((long long)(32 + (t >> 3)) * 256 + d) * 32 + kk;
    *(u16x4*)(Tb + oE) = he;
    *(u16x4*)(Tb + oO) = ho;
    *(u16x4*)(Tb + 524288 + oE) = le;
    *(u16x4*)(Tb + 524288 + oO) = lo4;
}

// ---------------------------------------------------------------------------
// FUSED column-norm + transpose + split:
// Yl[B][D=256][C] -> Ylt planes [B][C][D] scaled by 1/||col||_D.
// ---------------------------------------------------------------------------
__global__ __launch_bounds__(256) void transnorm_k(const float* __restrict__ Yl,
                                                   u16* __restrict__ hi, u16* __restrict__ lo) {
    __shared__ float tile[256][33];
    __shared__ float part[8][33];
    __shared__ float invn[32];
    int c0 = blockIdx.x * 32, b = blockIdx.y;
    int t = threadIdx.x;
    int tx = t & 31, ty = t >> 5;
    const float* base = Yl + (long long)b * DD * CC + c0;
    for (int d = ty; d < 256; d += 8)
        tile[d][tx] = base[(long long)d * CC + tx];
    __syncthreads();
    float s = 0.0f;
    #pragma unroll
    for (int dd = 0; dd < 32; ++dd) {
        float v = tile[ty * 32 + dd][tx];
        s += v * v;
    }
    part[ty][tx] = s;
    __syncthreads();
    if (ty == 0) {
        float tot = part[0][tx] + part[1][tx] + part[2][tx] + part[3][tx]
                  + part[4][tx] + part[5][tx] + part[6][tx] + part[7][tx];
        invn[tx] = 1.0f / fmaxf(sqrtf(tot), 1e-12f);
    }
    __syncthreads();
    long long ob = (long long)b * DD * CC;
    #pragma unroll 4
    for (int i = 0; i < 32; ++i) {
        float v = tile[t][i] * invn[i];
        unsigned short hh, ll; split2(v, hh, ll);
        long long o = ob + (long long)(c0 + i) * DD + t;
        hi[o] = hh; lo[o] = ll;
    }
}

// ---------------------------------------------------------------------------
// Sum 2 K-split parts of latent [B][D][HW] -> split planes + transposed planes
// ---------------------------------------------------------------------------
__global__ __launch_bounds__(256) void latreduce_k(const float* __restrict__ parts,
                                                   u16* __restrict__ hi, u16* __restrict__ lo,
                                                   u16* __restrict__ thi, u16* __restrict__ tlo) {
    __shared__ float tile[32][33];
    int h0 = blockIdx.x * 32, d0 = blockIdx.y * 32, b = blockIdx.z;
    const long long sL = (long long)DD * HWW;
    const long long ps = (long long)BB * sL;
    const float* base = parts + (long long)b * sL;
    int tx = threadIdx.x & 31, ty = threadIdx.x >> 5;
    for (int i = ty; i < 32; i += 8) {
        long long o = (long long)(d0 + i) * HWW + h0 + tx;
        float s = base[o] + base[o + ps];
        tile[i][tx] = s;
        unsigned short hh, ll; split2(s, hh, ll);
        long long od = (long long)b * sL + o;
        hi[od] = hh; lo[od] = ll;
    }
    __syncthreads();
    for (int i = ty; i < 32; i += 8) {
        float v = tile[tx][i];
        unsigned short hh, ll; split2(v, hh, ll);
        long long ot = (long long)b * sL + (long long)(h0 + i) * DD + d0 + tx;
        thi[ot] = hh; tlo[ot] = ll;
    }
}

// ---------------------------------------------------------------------------
__global__ __launch_bounds__(256) void latnorm_k(const float* __restrict__ G,
                                                 float* __restrict__ rs) {
    int i = blockIdx.x * 256 + threadIdx.x;
    int b = i >> 8, d = i & 255;
    float v = G[((long long)b * DD + d) * DD + d];
    rs[i] = 1.0f / fmaxf(sqrtf(v), 1e-12f);
}

// softmax over gram rows -> aff hi/lo planes
__global__ __launch_bounds__(256) void softmax_k(const float* __restrict__ G,
                                                 const float* __restrict__ rs,
                                                 u16* __restrict__ affHi,
                                                 u16* __restrict__ affLo) {
    int d = blockIdx.x, b = blockIdx.y;
    const float* row = G + ((long long)b * DD + d) * DD;
    const float* rsb = rs + (long long)b * DD;
    int t = threadIdx.x;
    float lg = row[t] * rsb[d] * rsb[t];

    float m = lg;
    for (int off = 32; off > 0; off >>= 1) m = fmaxf(m, __shfl_down(m, off, 64));
    __shared__ float wsm[4];
    __shared__ float bm, bs;
    int lane = t & 63, w = t >> 6;
    if (lane == 0) wsm[w] = m;
    __syncthreads();
    if (t == 0) bm = fmaxf(fmaxf(wsm[0], wsm[1]), fmaxf(wsm[2], wsm[3]));
    __syncthreads();
    float e = expf(lg - bm);
    float s = e;
    for (int off = 32; off > 0; off >>= 1) s += __shfl_down(s, off, 64);
    if (lane == 0) wsm[w] = s;
    __syncthreads();
    if (t == 0) bs = wsm[0] + wsm[1] + wsm[2] + wsm[3];
    __syncthreads();
    float v = e / bs;
    unsigned short hh, ll; split2(v, hh, ll);
    long long o = ((long long)b * DD + d) * DD + t;
    affHi[o] = hh; affLo[o] = ll;
}

// ---------------------------------------------------------------------------
extern "C" void kernel_launch(void* const* d_in, const int* in_sizes, int n_in,
                              void* d_out, int out_size, void* d_ws, size_t ws_size,
                              hipStream_t stream) {
    const float* v2l   = (const float*)d_in[0];
    const float* l2v   = (const float*)d_in[1];
    const float* w_v2l = (const float*)d_in[2];
    const float* g_v2l = (const float*)d_in[3];
    const float* b_v2l = (const float*)d_in[4];
    const float* w_l2v = (const float*)d_in[5];
    const float* g_l2v = (const float*)d_in[6];
    const float* b_l2v = (const float*)d_in[7];
    float* out = (float*)d_out;

    // d_out scratch: latPart (2 x 32MB at offset 0) + YvT tiled planes (32MB at 64MB)
    float* latPart = (float*)d_out;
    u16*   YvT     = (u16*)((char*)d_out + 67108864);

    char* W = (char*)d_ws;
    float* Yv     = (float*)(W + 0);            // 32MB fp32
    float* Yl     = (float*)(W + 33554432);     // 32MB
    u16*   YltHi  = (u16*)(W + 67108864);       // 16MB
    u16*   YltLo  = (u16*)(W + 83886080);       // 16MB
    u16*   latHi  = (u16*)(W + 100663296);      //  8MB
    u16*   latLo  = (u16*)(W + 109051904);      //  8MB
    u16*   latTHi = (u16*)(W + 117440512);      //  8MB
    u16*   latTLo = (u16*)(W + 125829120);      //  8MB
    u16*   l2tHi  = (u16*)(W + 134217728);      //  8MB
    u16*   l2tLo  = (u16*)(W + 142606336);      //  8MB
    float* gram   = (float*)(W + 150994944);    //  4MB
    float* rs     = (float*)(W + 155189248);
    u16*   affHi  = (u16*)(W + 155336704);      //  2MB
    u16*   affLo  = (u16*)(W + 157433856);      //  2MB
    u16*   WvHi   = (u16*)(W + 159531008);      //  512KB each
    u16*   WvLo   = WvHi + 262144;
    u16*   WlHi   = WvLo + 262144;
    u16*   WlLo   = WlHi + 262144;

    const long long sY   = (long long)DD * CC;     // 524288
    const long long sL   = (long long)DD * HWW;    // 262144
    const long long sG   = (long long)DD * DD;     // 65536
    const long long sX   = (long long)CC * HWW;    // 2097152

    // weights -> planes
    split_k<<<128, 256, 0, stream>>>(w_v2l, WvHi, WvLo, 32768);
    split_k<<<128, 256, 0, stream>>>(w_l2v, WlHi, WlLo, 32768);

    // G1+G2 fused (B hi-only, 2-term): Yv/Yl = relu(sc*(W . X^T)+b)
    gemm2b<0, 1, 1, 1, 0, 0><<<dim3(CC / 128, DD / 128, 32), 512, 0, stream>>>(
        WvHi, WvLo, WlHi, WlLo, 0, HWW,
        v2l, nullptr, l2v, nullptr, sX, HWW,
        Yv, Yl, sY, 0, CC, HWW,
        g_v2l, b_v2l, g_l2v, b_l2v);

    rownorm_split_tiled_k<<<dim3(DD, BB), 256, 0, stream>>>(Yv, YvT);
    transnorm_k<<<dim3(CC / 32, BB), 256, 0, stream>>>(Yl, YltHi, YltLo);

    // G3 (K-split x2, tiled A, B hi-only): latent parts = Yvn(k') . B'(k')^T
    gemm2b<0, 0, 0, 2, 1, 0><<<dim3(HWW / 128, DD / 128, 32), 512, 0, stream>>>(
        YvT, YvT + 524288, nullptr, nullptr, 1048576, 32,
        v2l, nullptr, nullptr, nullptr, sX, HWW,
        latPart, nullptr, sL, (long long)BB * sL, HWW, 1024,
        nullptr, nullptr, nullptr, nullptr);

    latreduce_k<<<dim3(HWW / 32, DD / 32, BB), 256, 0, stream>>>(
        latPart, latHi, latLo, latTHi, latTLo);

    // gram = latent . latent^T  (plane MFMA, fp32 out)
    mfma_gemm<64, 0><<<dim3(4, 2, BB), 256, 0, stream>>>(
        latHi, latLo, sL, HWW, latHi, latLo, sL, HWW,
        gram, nullptr, sG, DD, HWW);

    latnorm_k<<<dim3(BB * DD / 256), 256, 0, stream>>>(gram, rs);
    softmax_k<<<dim3(DD, BB), 256, 0, stream>>>(gram, rs, affHi, affLo);

    // lat2t = latentT . aff^T  [HW,D] -> planes
    mfma_gemm<128, 2><<<dim3(2, 8, BB), 256, 0, stream>>>(
        latTHi, latTLo, sL, DD, affHi, affLo, sG, DD,
        l2tHi, l2tLo, sL, DD, DD);

    // G6 (B planes via gload, 2-TERM now): out = Ylt . l2t^T  [C=2048 x HW=1024]
    gemm2b<1, 0, 0, 1, 0, 0><<<dim3(HWW / 128, CC / 128, BB), 512, 0, stream>>>(
        YltHi, YltLo, nullptr, nullptr, sY, DD,
        l2tHi, nullptr, nullptr, nullptr, sL, DD,
        out, nullptr, sX, 0, HWW, DD,
        nullptr, nullptr, nullptr, nullptr);
}